// Round 1
// baseline (552.423 us; speedup 1.0000x reference)
//
#include <hip/hip_runtime.h>
#include <hip/hip_bf16.h>
#include <cstdint>
#include <cstddef>

#define N_NODES 50000
#define NEG_SLOPE 0.2f

// ---------------------------------------------------------------------------
// CSR build: degree count -> exclusive scan -> scatter
// ---------------------------------------------------------------------------
__global__ void count_deg_kernel(const int* __restrict__ ei, int E0, int E,
                                 int* __restrict__ deg) {
    int e = blockIdx.x * blockDim.x + threadIdx.x;
    if (e >= E) return;
    int d = (e < E0) ? ei[E0 + e] : (e - E0);
    atomicAdd(&deg[d], 1);
}

__global__ __launch_bounds__(1024) void scan_kernel(const int* __restrict__ deg,
                                                    int* __restrict__ rowptr, int n) {
    const int T = 1024;
    __shared__ int buf[T];
    __shared__ int carry;
    int t = threadIdx.x;
    if (t == 0) carry = 0;
    __syncthreads();
    for (int base = 0; base < n; base += T) {
        int v = (base + t < n) ? deg[base + t] : 0;
        int x = v;
        for (int off = 1; off < T; off <<= 1) {
            buf[t] = x;
            __syncthreads();
            int y = (t >= off) ? buf[t - off] : 0;
            __syncthreads();
            x += y;
        }
        int c = carry;
        if (base + t < n) rowptr[base + t] = c + x - v;  // exclusive prefix
        __syncthreads();            // everyone read carry
        if (t == T - 1) carry = c + x;
        __syncthreads();
    }
    if (t == 0) rowptr[n] = carry;
}

__global__ void scatter_kernel(const int* __restrict__ ei, int E0, int E,
                               const int* __restrict__ rowptr,
                               int* __restrict__ fill, int* __restrict__ csr_src) {
    int e = blockIdx.x * blockDim.x + threadIdx.x;
    if (e >= E) return;
    int s, d;
    if (e < E0) { s = ei[e]; d = ei[E0 + e]; }
    else        { s = e - E0; d = e - E0; }
    int pos = atomicAdd(&fill[d], 1);
    csr_src[rowptr[d] + pos] = s;
}

// ---------------------------------------------------------------------------
// fp32 tiled GEMM: C[M,N] = A[M,K] * B[N,K]^T   (both row-major)
// BM=BN=64, BK=16, TM=TN=4, 256 threads
// ---------------------------------------------------------------------------
template <int BM, int BN, int BK, int TM, int TN>
__global__ __launch_bounds__(256) void gemm_abt_kernel(
    const float* __restrict__ A, const float* __restrict__ B,
    float* __restrict__ C, int M, int N, int K) {
    const int bm = blockIdx.y * BM;
    const int bn = blockIdx.x * BN;
    __shared__ float As[BK][BM + 1];
    __shared__ float Bs[BK][BN + 1];
    const int tx = threadIdx.x % (BN / TN);
    const int ty = threadIdx.x / (BN / TN);
    float acc[TM][TN] = {};
    for (int k0 = 0; k0 < K; k0 += BK) {
        for (int idx = threadIdx.x; idx < BM * BK; idx += 256) {
            int i = idx / BK, j = idx % BK;
            int r = bm + i;
            As[j][i] = (r < M) ? A[(size_t)r * K + k0 + j] : 0.f;
        }
        for (int idx = threadIdx.x; idx < BN * BK; idx += 256) {
            int i = idx / BK, j = idx % BK;
            int r = bn + i;
            Bs[j][i] = (r < N) ? B[(size_t)r * K + k0 + j] : 0.f;
        }
        __syncthreads();
        for (int kk = 0; kk < BK; ++kk) {
            float a[TM], b[TN];
#pragma unroll
            for (int i = 0; i < TM; i++) a[i] = As[kk][ty * TM + i];
#pragma unroll
            for (int j = 0; j < TN; j++) b[j] = Bs[kk][tx * TN + j];
#pragma unroll
            for (int i = 0; i < TM; i++)
#pragma unroll
                for (int j = 0; j < TN; j++) acc[i][j] += a[i] * b[j];
        }
        __syncthreads();
    }
    for (int i = 0; i < TM; i++) {
        int r = bm + ty * TM + i;
        if (r >= M) continue;
        for (int j = 0; j < TN; j++) {
            int c = bn + tx * TN + j;
            if (c < N) C[(size_t)r * N + c] = acc[i][j];
        }
    }
}

// ---------------------------------------------------------------------------
// Attention coefficients, layer 1: a_src/a_dst [N,4] from h1 [N,128]
// thread i = n*4+h
// ---------------------------------------------------------------------------
__global__ void att1_kernel(const float* __restrict__ h1,
                            const float* __restrict__ att_src,
                            const float* __restrict__ att_dst,
                            float* __restrict__ a_src, float* __restrict__ a_dst,
                            int N) {
    int i = blockIdx.x * blockDim.x + threadIdx.x;
    if (i >= N * 4) return;
    int h = i & 3;
    const float4* hp = (const float4*)(h1 + (size_t)i * 32);
    const float4* as = (const float4*)(att_src + h * 32);
    const float4* ad = (const float4*)(att_dst + h * 32);
    float ssum = 0.f, dsum = 0.f;
#pragma unroll
    for (int j = 0; j < 8; j++) {
        float4 hv = hp[j], av = as[j], dv = ad[j];
        ssum += hv.x * av.x + hv.y * av.y + hv.z * av.z + hv.w * av.w;
        dsum += hv.x * dv.x + hv.y * dv.y + hv.z * dv.z + hv.w * dv.w;
    }
    a_src[i] = ssum;
    a_dst[i] = dsum;
}

// layer 2: h2 [N,40], att vectors length 40
__global__ void att2_kernel(const float* __restrict__ h2,
                            const float* __restrict__ att_src,
                            const float* __restrict__ att_dst,
                            float* __restrict__ a_src, float* __restrict__ a_dst,
                            int N) {
    int n = blockIdx.x * blockDim.x + threadIdx.x;
    if (n >= N) return;
    const float4* hp = (const float4*)(h2 + (size_t)n * 40);
    const float4* as = (const float4*)att_src;
    const float4* ad = (const float4*)att_dst;
    float ssum = 0.f, dsum = 0.f;
#pragma unroll
    for (int j = 0; j < 10; j++) {
        float4 hv = hp[j], av = as[j], dv = ad[j];
        ssum += hv.x * av.x + hv.y * av.y + hv.z * av.z + hv.w * av.w;
        dsum += hv.x * dv.x + hv.y * dv.y + hv.z * dv.z + hv.w * dv.w;
    }
    a_src[n] = ssum;
    a_dst[n] = dsum;
}

// ---------------------------------------------------------------------------
// Aggregation layer 1: per-node softmax over incoming edges, 4 heads x 32 dim
// block = 128 threads (t = h*32+d), one block per node. Writes z = relu(out+b1)
// ---------------------------------------------------------------------------
__global__ __launch_bounds__(128) void agg1_kernel(
    const float* __restrict__ h1, const float* __restrict__ a_src,
    const float* __restrict__ a_dst, const int* __restrict__ rowptr,
    const int* __restrict__ csr_src, const float* __restrict__ b1,
    float* __restrict__ z) {
    const int CH = 512;
    __shared__ int s_src[CH];
    int n = blockIdx.x;
    int t = threadIdx.x;
    int h = t >> 5;
    float adn = a_dst[n * 4 + h];
    int beg = rowptr[n];
    int deg = rowptr[n + 1] - beg;

    // phase A: per-head max of leaky_relu(a_src[s]+a_dst[n])
    float m = -1e30f;
    for (int c0 = 0; c0 < deg; c0 += CH) {
        int cnt = min(CH, deg - c0);
        __syncthreads();
        for (int i = t; i < cnt; i += 128) s_src[i] = csr_src[beg + c0 + i];
        __syncthreads();
        int d = t & 31;
        for (int i = d; i < cnt; i += 32) {
            float l = a_src[s_src[i] * 4 + h] + adn;
            l = l > 0.f ? l : NEG_SLOPE * l;
            m = fmaxf(m, l);
        }
    }
#pragma unroll
    for (int off = 16; off > 0; off >>= 1) m = fmaxf(m, __shfl_xor(m, off, 32));

    // phase B: accumulate sum(w) and sum(w * h1[src])
    float acc = 0.f, den = 0.f;
    for (int c0 = 0; c0 < deg; c0 += CH) {
        int cnt = min(CH, deg - c0);
        __syncthreads();
        for (int i = t; i < cnt; i += 128) s_src[i] = csr_src[beg + c0 + i];
        __syncthreads();
        for (int i = 0; i < cnt; i++) {
            int s = s_src[i];
            float l = a_src[s * 4 + h] + adn;
            l = l > 0.f ? l : NEG_SLOPE * l;
            float w = __expf(l - m);
            den += w;
            acc += w * h1[(size_t)s * 128 + t];
        }
    }
    float o = acc / den + b1[t];
    z[(size_t)n * 128 + t] = fmaxf(o, 0.f);   // layer-1 ReLU fused
}

// ---------------------------------------------------------------------------
// Aggregation layer 2: H=1, D=40. One wave (64 threads) per node. Writes d_out.
// ---------------------------------------------------------------------------
__global__ __launch_bounds__(64) void agg2_kernel(
    const float* __restrict__ h2, const float* __restrict__ a_src,
    const float* __restrict__ a_dst, const int* __restrict__ rowptr,
    const int* __restrict__ csr_src, const float* __restrict__ b2,
    float* __restrict__ out) {
    const int CH = 512;
    __shared__ int s_src[CH];
    int n = blockIdx.x;
    int t = threadIdx.x;  // 0..63
    float adn = a_dst[n];
    int beg = rowptr[n];
    int deg = rowptr[n + 1] - beg;

    float m = -1e30f;
    for (int c0 = 0; c0 < deg; c0 += CH) {
        int cnt = min(CH, deg - c0);
        __syncthreads();
        for (int i = t; i < cnt; i += 64) s_src[i] = csr_src[beg + c0 + i];
        __syncthreads();
        for (int i = t; i < cnt; i += 64) {
            float l = a_src[s_src[i]] + adn;
            l = l > 0.f ? l : NEG_SLOPE * l;
            m = fmaxf(m, l);
        }
    }
#pragma unroll
    for (int off = 32; off > 0; off >>= 1) m = fmaxf(m, __shfl_xor(m, off, 64));

    float acc = 0.f, den = 0.f;
    for (int c0 = 0; c0 < deg; c0 += CH) {
        int cnt = min(CH, deg - c0);
        __syncthreads();
        for (int i = t; i < cnt; i += 64) s_src[i] = csr_src[beg + c0 + i];
        __syncthreads();
        for (int i = 0; i < cnt; i++) {
            int s = s_src[i];
            float l = a_src[s] + adn;
            l = l > 0.f ? l : NEG_SLOPE * l;
            float w = __expf(l - m);
            den += w;
            if (t < 40) acc += w * h2[(size_t)s * 40 + t];
        }
    }
    if (t < 40) out[(size_t)n * 40 + t] = acc / den + b2[t];
}

// ---------------------------------------------------------------------------
extern "C" void kernel_launch(void* const* d_in, const int* in_sizes, int n_in,
                              void* d_out, int out_size, void* d_ws, size_t ws_size,
                              hipStream_t stream) {
    const float* x        = (const float*)d_in[0];   // [50000,256]
    const int*   ei       = (const int*)d_in[1];     // [2,E0]
    const float* W1       = (const float*)d_in[2];   // [128,256]
    const float* att_src1 = (const float*)d_in[3];   // [4,32]
    const float* att_dst1 = (const float*)d_in[4];   // [4,32]
    const float* b1       = (const float*)d_in[5];   // [128]
    const float* W2       = (const float*)d_in[6];   // [40,128]
    const float* att_src2 = (const float*)d_in[7];   // [1,40]
    const float* att_dst2 = (const float*)d_in[8];   // [1,40]
    const float* b2       = (const float*)d_in[9];   // [40]
    float* out = (float*)d_out;

    const int N  = N_NODES;
    const int E0 = in_sizes[1] / 2;   // 800000
    const int E  = E0 + N;            // + self loops

    // workspace layout (bytes, 16B-aligned)
    char* ws = (char*)d_ws;
    float* h1      = (float*)(ws + 0);             // 25,600,000
    float* z       = (float*)(ws + 25600000);      // 25,600,000
    float* h2      = (float*)(ws + 51200000);      //  8,000,000
    float* a_src1  = (float*)(ws + 59200000);      //    800,000
    float* a_dst1  = (float*)(ws + 60000000);      //    800,000
    float* a_src2  = (float*)(ws + 60800000);      //    200,000
    float* a_dst2  = (float*)(ws + 61000000);      //    200,000
    int*   deg     = (int*)  (ws + 61200000);      //    200,000
    int*   fill    = (int*)  (ws + 61400000);      //    200,000
    int*   rowptr  = (int*)  (ws + 61600000);      //    200,004
    int*   csr_src = (int*)  (ws + 61800192);      //  3,400,000

    // zero deg + fill (adjacent, 400 KB)
    hipMemsetAsync(deg, 0, 400000, stream);

    // CSR build
    count_deg_kernel<<<(E + 255) / 256, 256, 0, stream>>>(ei, E0, E, deg);
    scan_kernel<<<1, 1024, 0, stream>>>(deg, rowptr, N);
    scatter_kernel<<<(E + 255) / 256, 256, 0, stream>>>(ei, E0, E, rowptr, fill, csr_src);

    // layer 1: h1 = x @ W1^T  [50000,128]
    {
        dim3 grid(128 / 64, (N + 63) / 64);
        gemm_abt_kernel<64, 64, 16, 4, 4><<<grid, 256, 0, stream>>>(x, W1, h1, N, 128, 256);
    }
    att1_kernel<<<(N * 4 + 255) / 256, 256, 0, stream>>>(h1, att_src1, att_dst1, a_src1, a_dst1, N);
    agg1_kernel<<<N, 128, 0, stream>>>(h1, a_src1, a_dst1, rowptr, csr_src, b1, z);

    // layer 2: h2 = z @ W2^T  [50000,40]
    {
        dim3 grid(1, (N + 63) / 64);
        gemm_abt_kernel<64, 64, 16, 4, 4><<<grid, 256, 0, stream>>>(z, W2, h2, N, 40, 128);
    }
    att2_kernel<<<(N + 255) / 256, 256, 0, stream>>>(h2, att_src2, att_dst2, a_src2, a_dst2, N);
    agg2_kernel<<<N, 64, 0, stream>>>(h2, a_src2, a_dst2, rowptr, csr_src, b2, out);
}

// Round 2
// 390.798 us; speedup vs baseline: 1.4136x; 1.4136x over previous
//
#include <hip/hip_runtime.h>
#include <hip/hip_bf16.h>
#include <cstdint>
#include <cstddef>

#define N_NODES 50000
#define NEG_SLOPE 0.2f

typedef float floatx4 __attribute__((ext_vector_type(4)));
typedef short shortx8 __attribute__((ext_vector_type(8)));

// ---- fp32 <-> bf16 helpers (RNE) --------------------------------------------
__device__ __forceinline__ unsigned short f2b(float f) {
    union { float f; unsigned u; } v; v.f = f;
    unsigned u = v.u;
    return (unsigned short)((u + 0x7FFFu + ((u >> 16) & 1u)) >> 16);
}
__device__ __forceinline__ float b2f(unsigned short b) {
    union { unsigned u; float f; } v; v.u = ((unsigned)b) << 16;
    return v.f;
}

// ---------------------------------------------------------------------------
// CSR build: degree count -> hierarchical scan -> scatter
// ---------------------------------------------------------------------------
__global__ void count_deg_kernel(const int* __restrict__ ei, int E0, int E,
                                 int* __restrict__ deg) {
    int e = blockIdx.x * blockDim.x + threadIdx.x;
    if (e >= E) return;
    int d = (e < E0) ? ei[E0 + e] : (e - E0);
    atomicAdd(&deg[d], 1);
}

__global__ void chunk_sum_kernel(const int* __restrict__ deg, int* __restrict__ csum, int n) {
    __shared__ int buf[256];
    int b = blockIdx.x, t = threadIdx.x;
    int base = b * 1024, s = 0;
    for (int i = t; i < 1024; i += 256) {
        int idx = base + i;
        s += (idx < n) ? deg[idx] : 0;
    }
    buf[t] = s; __syncthreads();
    for (int off = 128; off > 0; off >>= 1) {
        if (t < off) buf[t] += buf[t + off];
        __syncthreads();
    }
    if (t == 0) csum[b] = buf[0];
}

__global__ void scan_chunks_kernel(const int* __restrict__ csum, int* __restrict__ coff,
                                   int* __restrict__ rowptr, int nchunks, int n) {
    if (threadIdx.x == 0 && blockIdx.x == 0) {
        int s = 0;
        for (int i = 0; i < nchunks; i++) { coff[i] = s; s += csum[i]; }
        rowptr[n] = s;
    }
}

__global__ __launch_bounds__(1024) void scan_write_kernel(const int* __restrict__ deg,
                                                          const int* __restrict__ coff,
                                                          int* __restrict__ rowptr, int n) {
    __shared__ int buf[1024];
    int b = blockIdx.x, t = threadIdx.x;
    int idx = b * 1024 + t;
    int v = (idx < n) ? deg[idx] : 0;
    int x = v;
    for (int off = 1; off < 1024; off <<= 1) {
        buf[t] = x; __syncthreads();
        int y = (t >= off) ? buf[t - off] : 0;
        __syncthreads();
        x += y;
    }
    if (idx < n) rowptr[idx] = coff[b] + x - v;  // exclusive
}

__global__ void scatter_kernel(const int* __restrict__ ei, int E0, int E,
                               const int* __restrict__ rowptr,
                               int* __restrict__ fill, int* __restrict__ csr_src) {
    int e = blockIdx.x * blockDim.x + threadIdx.x;
    if (e >= E) return;
    int s, d;
    if (e < E0) { s = ei[e]; d = ei[E0 + e]; }
    else        { s = e - E0; d = e - E0; }
    int pos = atomicAdd(&fill[d], 1);
    csr_src[rowptr[d] + pos] = s;
}

// ---------------------------------------------------------------------------
// MFMA split-bf16 GEMM:  Cb[M, NREAL](bf16) = A[M,KK](fp32) x B[NREAL,KK]^T(fp32)
// A,B are decomposed on the fly into bf16 hi+lo; D = Ah*Bh + Ah*Bl + Al*Bh
// (relative error ~2^-16, fp32-quality). BM=128, BK=64, 256 threads / 4 waves,
// wave w computes rows [w*32, w*32+32) x all BN cols via 16x16x32 MFMA.
// ---------------------------------------------------------------------------
template <int BN, int NREAL, int KK>
__global__ __launch_bounds__(256) void gemm_mfma_kernel(
    const float* __restrict__ A, const float* __restrict__ B,
    unsigned short* __restrict__ Cb, int M) {
    const int BM = 128, BK = 64, LDK = 72;  // 72*2=144B stride: 16B-aligned, conflict-light
    const int NT = BN / 16;
    __shared__ unsigned short As_hi[BM * LDK], As_lo[BM * LDK];
    __shared__ unsigned short Bs_hi[BN * LDK], Bs_lo[BN * LDK];
    const int t = threadIdx.x;
    const int wave = t >> 6, lane = t & 63;
    const int lrow = lane & 15, lkg = lane >> 4;
    const int bm = blockIdx.x * BM;

    floatx4 acc[2][NT] = {};

    for (int k0 = 0; k0 < KK; k0 += BK) {
        __syncthreads();  // previous iteration's ds_reads done before overwrite
        // stage A tile: BM x 64 fp32 -> hi/lo bf16
        for (int i = t; i < BM * 16; i += 256) {
            int r = i >> 4, c4 = (i & 15) << 2;
            int gr = bm + r;
            float4 v = make_float4(0.f, 0.f, 0.f, 0.f);
            if (gr < M) v = *(const float4*)&A[(size_t)gr * KK + k0 + c4];
            unsigned short h0 = f2b(v.x), h1 = f2b(v.y), h2 = f2b(v.z), h3 = f2b(v.w);
            unsigned short l0 = f2b(v.x - b2f(h0)), l1 = f2b(v.y - b2f(h1));
            unsigned short l2 = f2b(v.z - b2f(h2)), l3 = f2b(v.w - b2f(h3));
            int o = r * LDK + c4;
            As_hi[o] = h0; As_hi[o + 1] = h1; As_hi[o + 2] = h2; As_hi[o + 3] = h3;
            As_lo[o] = l0; As_lo[o + 1] = l1; As_lo[o + 2] = l2; As_lo[o + 3] = l3;
        }
        // stage B tile: BN x 64
        for (int i = t; i < BN * 16; i += 256) {
            int r = i >> 4, c4 = (i & 15) << 2;
            float4 v = make_float4(0.f, 0.f, 0.f, 0.f);
            if (r < NREAL) v = *(const float4*)&B[(size_t)r * KK + k0 + c4];
            unsigned short h0 = f2b(v.x), h1 = f2b(v.y), h2 = f2b(v.z), h3 = f2b(v.w);
            unsigned short l0 = f2b(v.x - b2f(h0)), l1 = f2b(v.y - b2f(h1));
            unsigned short l2 = f2b(v.z - b2f(h2)), l3 = f2b(v.w - b2f(h3));
            int o = r * LDK + c4;
            Bs_hi[o] = h0; Bs_hi[o + 1] = h1; Bs_hi[o + 2] = h2; Bs_hi[o + 3] = h3;
            Bs_lo[o] = l0; Bs_lo[o + 1] = l1; Bs_lo[o + 2] = l2; Bs_lo[o + 3] = l3;
        }
        __syncthreads();

        for (int ks = 0; ks < BK; ks += 32) {
            int kc = ks + lkg * 8;
            shortx8 ah[2], al[2];
#pragma unroll
            for (int mt = 0; mt < 2; mt++) {
                int row = wave * 32 + mt * 16 + lrow;
                ah[mt] = *(const shortx8*)&As_hi[row * LDK + kc];
                al[mt] = *(const shortx8*)&As_lo[row * LDK + kc];
            }
#pragma unroll
            for (int nt = 0; nt < NT; nt++) {
                int col = nt * 16 + lrow;
                shortx8 bh = *(const shortx8*)&Bs_hi[col * LDK + kc];
                shortx8 bl = *(const shortx8*)&Bs_lo[col * LDK + kc];
#pragma unroll
                for (int mt = 0; mt < 2; mt++) {
                    acc[mt][nt] = __builtin_amdgcn_mfma_f32_16x16x32_bf16(ah[mt], bh, acc[mt][nt], 0, 0, 0);
                    acc[mt][nt] = __builtin_amdgcn_mfma_f32_16x16x32_bf16(ah[mt], bl, acc[mt][nt], 0, 0, 0);
                    acc[mt][nt] = __builtin_amdgcn_mfma_f32_16x16x32_bf16(al[mt], bh, acc[mt][nt], 0, 0, 0);
                }
            }
        }
    }
    // epilogue: C/D layout col=lane&15, row=(lane>>4)*4+reg (m89-verified)
#pragma unroll
    for (int mt = 0; mt < 2; mt++)
#pragma unroll
        for (int nt = 0; nt < NT; nt++)
#pragma unroll
            for (int r = 0; r < 4; r++) {
                int row = bm + wave * 32 + mt * 16 + lkg * 4 + r;
                int col = nt * 16 + lrow;
                if (row < M && col < NREAL)
                    Cb[(size_t)row * NREAL + col] = f2b(acc[mt][nt][r]);
            }
}

// ---------------------------------------------------------------------------
// Attention coefficients from bf16 h
// layer 1: h1b [N,128] bf16, thread i = n*4+h over 32 dims
// ---------------------------------------------------------------------------
__global__ void att1_kernel(const unsigned short* __restrict__ h1b,
                            const float* __restrict__ att_src,
                            const float* __restrict__ att_dst,
                            float* __restrict__ a_src, float* __restrict__ a_dst,
                            int N) {
    int i = blockIdx.x * blockDim.x + threadIdx.x;
    if (i >= N * 4) return;
    int h = i & 3;
    const ushort4* hp = (const ushort4*)(h1b + (size_t)i * 32);
    const float4* as = (const float4*)(att_src + h * 32);
    const float4* ad = (const float4*)(att_dst + h * 32);
    float ssum = 0.f, dsum = 0.f;
#pragma unroll
    for (int j = 0; j < 8; j++) {
        ushort4 hv = hp[j];
        float4 av = as[j], dv = ad[j];
        float x0 = b2f(hv.x), x1 = b2f(hv.y), x2 = b2f(hv.z), x3 = b2f(hv.w);
        ssum += x0 * av.x + x1 * av.y + x2 * av.z + x3 * av.w;
        dsum += x0 * dv.x + x1 * dv.y + x2 * dv.z + x3 * dv.w;
    }
    a_src[i] = ssum;
    a_dst[i] = dsum;
}

// layer 2: h2b [N,40] bf16
__global__ void att2_kernel(const unsigned short* __restrict__ h2b,
                            const float* __restrict__ att_src,
                            const float* __restrict__ att_dst,
                            float* __restrict__ a_src, float* __restrict__ a_dst,
                            int N) {
    int n = blockIdx.x * blockDim.x + threadIdx.x;
    if (n >= N) return;
    const ushort4* hp = (const ushort4*)(h2b + (size_t)n * 40);
    const float4* as = (const float4*)att_src;
    const float4* ad = (const float4*)att_dst;
    float ssum = 0.f, dsum = 0.f;
#pragma unroll
    for (int j = 0; j < 10; j++) {
        ushort4 hv = hp[j];
        float4 av = as[j], dv = ad[j];
        float x0 = b2f(hv.x), x1 = b2f(hv.y), x2 = b2f(hv.z), x3 = b2f(hv.w);
        ssum += x0 * av.x + x1 * av.y + x2 * av.z + x3 * av.w;
        dsum += x0 * dv.x + x1 * dv.y + x2 * dv.z + x3 * dv.w;
    }
    a_src[n] = ssum;
    a_dst[n] = dsum;
}

// ---------------------------------------------------------------------------
// Aggregation layer 1: softmax over incoming edges, 4 heads x 32 dim
// block = 128 threads (t = h*32+d), one block per node. z = relu(out + b1)
// ---------------------------------------------------------------------------
__global__ __launch_bounds__(128) void agg1_kernel(
    const unsigned short* __restrict__ h1b, const float* __restrict__ a_src,
    const float* __restrict__ a_dst, const int* __restrict__ rowptr,
    const int* __restrict__ csr_src, const float* __restrict__ b1,
    float* __restrict__ z) {
    const int CH = 512;
    __shared__ int s_src[CH];
    int n = blockIdx.x;
    int t = threadIdx.x;
    int h = t >> 5;
    float adn = a_dst[n * 4 + h];
    int beg = rowptr[n];
    int deg = rowptr[n + 1] - beg;

    // phase A: per-head max of leaky_relu(a_src[s]+a_dst[n])
    float m = -1e30f;
    for (int c0 = 0; c0 < deg; c0 += CH) {
        int cnt = min(CH, deg - c0);
        __syncthreads();
        for (int i = t; i < cnt; i += 128) s_src[i] = csr_src[beg + c0 + i];
        __syncthreads();
        int d = t & 31;
        for (int i = d; i < cnt; i += 32) {
            float l = a_src[s_src[i] * 4 + h] + adn;
            l = l > 0.f ? l : NEG_SLOPE * l;
            m = fmaxf(m, l);
        }
    }
#pragma unroll
    for (int off = 16; off > 0; off >>= 1) m = fmaxf(m, __shfl_xor(m, off, 32));

    // phase B: accumulate sum(w) and sum(w * h1[src])
    float acc = 0.f, den = 0.f;
    for (int c0 = 0; c0 < deg; c0 += CH) {
        int cnt = min(CH, deg - c0);
        __syncthreads();
        for (int i = t; i < cnt; i += 128) s_src[i] = csr_src[beg + c0 + i];
        __syncthreads();
        for (int i = 0; i < cnt; i++) {
            int s = s_src[i];
            float l = a_src[s * 4 + h] + adn;
            l = l > 0.f ? l : NEG_SLOPE * l;
            float w = __expf(l - m);
            den += w;
            acc += w * b2f(h1b[(size_t)s * 128 + t]);
        }
    }
    float o = acc / den + b1[t];
    z[(size_t)n * 128 + t] = fmaxf(o, 0.f);   // layer-1 ReLU fused
}

// ---------------------------------------------------------------------------
// Aggregation layer 2: H=1, D=40. One wave per node. Writes d_out (fp32).
// ---------------------------------------------------------------------------
__global__ __launch_bounds__(64) void agg2_kernel(
    const unsigned short* __restrict__ h2b, const float* __restrict__ a_src,
    const float* __restrict__ a_dst, const int* __restrict__ rowptr,
    const int* __restrict__ csr_src, const float* __restrict__ b2,
    float* __restrict__ out) {
    const int CH = 512;
    __shared__ int s_src[CH];
    int n = blockIdx.x;
    int t = threadIdx.x;  // 0..63
    float adn = a_dst[n];
    int beg = rowptr[n];
    int deg = rowptr[n + 1] - beg;

    float m = -1e30f;
    for (int c0 = 0; c0 < deg; c0 += CH) {
        int cnt = min(CH, deg - c0);
        __syncthreads();
        for (int i = t; i < cnt; i += 64) s_src[i] = csr_src[beg + c0 + i];
        __syncthreads();
        for (int i = t; i < cnt; i += 64) {
            float l = a_src[s_src[i]] + adn;
            l = l > 0.f ? l : NEG_SLOPE * l;
            m = fmaxf(m, l);
        }
    }
#pragma unroll
    for (int off = 32; off > 0; off >>= 1) m = fmaxf(m, __shfl_xor(m, off, 64));

    float acc = 0.f, den = 0.f;
    for (int c0 = 0; c0 < deg; c0 += CH) {
        int cnt = min(CH, deg - c0);
        __syncthreads();
        for (int i = t; i < cnt; i += 64) s_src[i] = csr_src[beg + c0 + i];
        __syncthreads();
        for (int i = 0; i < cnt; i++) {
            int s = s_src[i];
            float l = a_src[s] + adn;
            l = l > 0.f ? l : NEG_SLOPE * l;
            float w = __expf(l - m);
            den += w;
            if (t < 40) acc += w * b2f(h2b[(size_t)s * 40 + t]);
        }
    }
    if (t < 40) out[(size_t)n * 40 + t] = acc / den + b2[t];
}

// ---------------------------------------------------------------------------
extern "C" void kernel_launch(void* const* d_in, const int* in_sizes, int n_in,
                              void* d_out, int out_size, void* d_ws, size_t ws_size,
                              hipStream_t stream) {
    const float* x        = (const float*)d_in[0];   // [50000,256]
    const int*   ei       = (const int*)d_in[1];     // [2,E0]
    const float* W1       = (const float*)d_in[2];   // [128,256]
    const float* att_src1 = (const float*)d_in[3];   // [4,32]
    const float* att_dst1 = (const float*)d_in[4];   // [4,32]
    const float* b1       = (const float*)d_in[5];   // [128]
    const float* W2       = (const float*)d_in[6];   // [40,128]
    const float* att_src2 = (const float*)d_in[7];   // [1,40]
    const float* att_dst2 = (const float*)d_in[8];   // [1,40]
    const float* b2       = (const float*)d_in[9];   // [40]
    float* out = (float*)d_out;

    const int N  = N_NODES;
    const int E0 = in_sizes[1] / 2;   // 800000
    const int E  = E0 + N;            // + self loops
    const int NCHUNK = (N + 1023) / 1024;  // 49

    // workspace layout (bytes)
    char* ws = (char*)d_ws;
    unsigned short* h1b   = (unsigned short*)(ws + 0);          // 12,800,000
    float*          z     = (float*)(ws + 12800000);            // 25,600,000
    unsigned short* h2b   = (unsigned short*)(ws + 38400000);   //  4,000,000
    float* a_src1 = (float*)(ws + 42400000);                    //    800,000
    float* a_dst1 = (float*)(ws + 43200000);                    //    800,000
    float* a_src2 = (float*)(ws + 44000000);                    //    200,000
    float* a_dst2 = (float*)(ws + 44200000);                    //    200,000
    int*   deg    = (int*)(ws + 44400000);                      //    200,000
    int*   fill   = (int*)(ws + 44600000);                      //    200,000
    int*   rowptr = (int*)(ws + 44800000);                      //    200,004
    int*   csum   = (int*)(ws + 45000192);                      //        512
    int*   coff   = (int*)(ws + 45000704);                      //        512
    int*   csr_src= (int*)(ws + 45001216);                      //  3,400,000
    // total ~48.4 MB

    // zero deg + fill (contiguous 400 KB)
    hipMemsetAsync(deg, 0, 400000, stream);

    // CSR build
    count_deg_kernel<<<(E + 255) / 256, 256, 0, stream>>>(ei, E0, E, deg);
    chunk_sum_kernel<<<NCHUNK, 256, 0, stream>>>(deg, csum, N);
    scan_chunks_kernel<<<1, 64, 0, stream>>>(csum, coff, rowptr, NCHUNK, N);
    scan_write_kernel<<<NCHUNK, 1024, 0, stream>>>(deg, coff, rowptr, N);
    scatter_kernel<<<(E + 255) / 256, 256, 0, stream>>>(ei, E0, E, rowptr, fill, csr_src);

    // layer 1: h1b = bf16(x @ W1^T)  [50000,128]
    gemm_mfma_kernel<128, 128, 256><<<(N + 127) / 128, 256, 0, stream>>>(x, W1, h1b, N);
    att1_kernel<<<(N * 4 + 255) / 256, 256, 0, stream>>>(h1b, att_src1, att_dst1, a_src1, a_dst1, N);
    agg1_kernel<<<N, 128, 0, stream>>>(h1b, a_src1, a_dst1, rowptr, csr_src, b1, z);

    // layer 2: h2b = bf16(z @ W2^T)  [50000,40]
    gemm_mfma_kernel<48, 40, 128><<<(N + 127) / 128, 256, 0, stream>>>(z, W2, h2b, N);
    att2_kernel<<<(N + 255) / 256, 256, 0, stream>>>(h2b, att_src2, att_dst2, a_src2, a_dst2, N);
    agg2_kernel<<<N, 64, 0, stream>>>(h2b, a_src2, a_dst2, rowptr, csr_src, b2, out);
}

// Round 3
// 357.570 us; speedup vs baseline: 1.5449x; 1.0929x over previous
//
#include <hip/hip_runtime.h>
#include <hip/hip_bf16.h>
#include <cstdint>
#include <cstddef>

#define N_NODES 50000
#define NEG_SLOPE 0.2f

typedef float floatx4 __attribute__((ext_vector_type(4)));
typedef short shortx8 __attribute__((ext_vector_type(8)));

// ---- fp32 <-> bf16 helpers (RNE) --------------------------------------------
__device__ __forceinline__ unsigned short f2b(float f) {
    union { float f; unsigned u; } v; v.f = f;
    unsigned u = v.u;
    return (unsigned short)((u + 0x7FFFu + ((u >> 16) & 1u)) >> 16);
}
__device__ __forceinline__ float b2f(unsigned short b) {
    union { unsigned u; float f; } v; v.u = ((unsigned)b) << 16;
    return v.f;
}

// ---------------------------------------------------------------------------
// CSR build: degree count -> hierarchical scan -> scatter
// ---------------------------------------------------------------------------
__global__ void count_deg_kernel(const int* __restrict__ ei, int E0, int E,
                                 int* __restrict__ deg) {
    int e = blockIdx.x * blockDim.x + threadIdx.x;
    if (e >= E) return;
    int d = (e < E0) ? ei[E0 + e] : (e - E0);
    atomicAdd(&deg[d], 1);
}

__global__ void chunk_sum_kernel(const int* __restrict__ deg, int* __restrict__ csum, int n) {
    __shared__ int buf[256];
    int b = blockIdx.x, t = threadIdx.x;
    int base = b * 1024, s = 0;
    for (int i = t; i < 1024; i += 256) {
        int idx = base + i;
        s += (idx < n) ? deg[idx] : 0;
    }
    buf[t] = s; __syncthreads();
    for (int off = 128; off > 0; off >>= 1) {
        if (t < off) buf[t] += buf[t + off];
        __syncthreads();
    }
    if (t == 0) csum[b] = buf[0];
}

__global__ void scan_chunks_kernel(const int* __restrict__ csum, int* __restrict__ coff,
                                   int* __restrict__ rowptr, int nchunks, int n) {
    if (threadIdx.x == 0 && blockIdx.x == 0) {
        int s = 0;
        for (int i = 0; i < nchunks; i++) { coff[i] = s; s += csum[i]; }
        rowptr[n] = s;
    }
}

__global__ __launch_bounds__(1024) void scan_write_kernel(const int* __restrict__ deg,
                                                          const int* __restrict__ coff,
                                                          int* __restrict__ rowptr, int n) {
    __shared__ int buf[1024];
    int b = blockIdx.x, t = threadIdx.x;
    int idx = b * 1024 + t;
    int v = (idx < n) ? deg[idx] : 0;
    int x = v;
    for (int off = 1; off < 1024; off <<= 1) {
        buf[t] = x; __syncthreads();
        int y = (t >= off) ? buf[t - off] : 0;
        __syncthreads();
        x += y;
    }
    if (idx < n) rowptr[idx] = coff[b] + x - v;  // exclusive
}

__global__ void scatter_kernel(const int* __restrict__ ei, int E0, int E,
                               const int* __restrict__ rowptr,
                               int* __restrict__ fill, int* __restrict__ csr_src) {
    int e = blockIdx.x * blockDim.x + threadIdx.x;
    if (e >= E) return;
    int s, d;
    if (e < E0) { s = ei[e]; d = ei[E0 + e]; }
    else        { s = e - E0; d = e - E0; }
    int pos = atomicAdd(&fill[d], 1);
    csr_src[rowptr[d] + pos] = s;
}

// ---------------------------------------------------------------------------
// MFMA split-bf16 GEMM:  Cb[M, NREAL](bf16) = A[M,KK](fp32) x B[NREAL,KK]^T(fp32)
// ---------------------------------------------------------------------------
template <int BN, int NREAL, int KK>
__global__ __launch_bounds__(256) void gemm_mfma_kernel(
    const float* __restrict__ A, const float* __restrict__ B,
    unsigned short* __restrict__ Cb, int M) {
    const int BM = 128, BK = 64, LDK = 72;
    const int NT = BN / 16;
    __shared__ unsigned short As_hi[BM * LDK], As_lo[BM * LDK];
    __shared__ unsigned short Bs_hi[BN * LDK], Bs_lo[BN * LDK];
    const int t = threadIdx.x;
    const int wave = t >> 6, lane = t & 63;
    const int lrow = lane & 15, lkg = lane >> 4;
    const int bm = blockIdx.x * BM;

    floatx4 acc[2][NT] = {};

    for (int k0 = 0; k0 < KK; k0 += BK) {
        __syncthreads();
        for (int i = t; i < BM * 16; i += 256) {
            int r = i >> 4, c4 = (i & 15) << 2;
            int gr = bm + r;
            float4 v = make_float4(0.f, 0.f, 0.f, 0.f);
            if (gr < M) v = *(const float4*)&A[(size_t)gr * KK + k0 + c4];
            unsigned short h0 = f2b(v.x), h1 = f2b(v.y), h2 = f2b(v.z), h3 = f2b(v.w);
            unsigned short l0 = f2b(v.x - b2f(h0)), l1 = f2b(v.y - b2f(h1));
            unsigned short l2 = f2b(v.z - b2f(h2)), l3 = f2b(v.w - b2f(h3));
            int o = r * LDK + c4;
            As_hi[o] = h0; As_hi[o + 1] = h1; As_hi[o + 2] = h2; As_hi[o + 3] = h3;
            As_lo[o] = l0; As_lo[o + 1] = l1; As_lo[o + 2] = l2; As_lo[o + 3] = l3;
        }
        for (int i = t; i < BN * 16; i += 256) {
            int r = i >> 4, c4 = (i & 15) << 2;
            float4 v = make_float4(0.f, 0.f, 0.f, 0.f);
            if (r < NREAL) v = *(const float4*)&B[(size_t)r * KK + k0 + c4];
            unsigned short h0 = f2b(v.x), h1 = f2b(v.y), h2 = f2b(v.z), h3 = f2b(v.w);
            unsigned short l0 = f2b(v.x - b2f(h0)), l1 = f2b(v.y - b2f(h1));
            unsigned short l2 = f2b(v.z - b2f(h2)), l3 = f2b(v.w - b2f(h3));
            int o = r * LDK + c4;
            Bs_hi[o] = h0; Bs_hi[o + 1] = h1; Bs_hi[o + 2] = h2; Bs_hi[o + 3] = h3;
            Bs_lo[o] = l0; Bs_lo[o + 1] = l1; Bs_lo[o + 2] = l2; Bs_lo[o + 3] = l3;
        }
        __syncthreads();

        for (int ks = 0; ks < BK; ks += 32) {
            int kc = ks + lkg * 8;
            shortx8 ah[2], al[2];
#pragma unroll
            for (int mt = 0; mt < 2; mt++) {
                int row = wave * 32 + mt * 16 + lrow;
                ah[mt] = *(const shortx8*)&As_hi[row * LDK + kc];
                al[mt] = *(const shortx8*)&As_lo[row * LDK + kc];
            }
#pragma unroll
            for (int nt = 0; nt < NT; nt++) {
                int col = nt * 16 + lrow;
                shortx8 bh = *(const shortx8*)&Bs_hi[col * LDK + kc];
                shortx8 bl = *(const shortx8*)&Bs_lo[col * LDK + kc];
#pragma unroll
                for (int mt = 0; mt < 2; mt++) {
                    acc[mt][nt] = __builtin_amdgcn_mfma_f32_16x16x32_bf16(ah[mt], bh, acc[mt][nt], 0, 0, 0);
                    acc[mt][nt] = __builtin_amdgcn_mfma_f32_16x16x32_bf16(ah[mt], bl, acc[mt][nt], 0, 0, 0);
                    acc[mt][nt] = __builtin_amdgcn_mfma_f32_16x16x32_bf16(al[mt], bh, acc[mt][nt], 0, 0, 0);
                }
            }
        }
    }
#pragma unroll
    for (int mt = 0; mt < 2; mt++)
#pragma unroll
        for (int nt = 0; nt < NT; nt++)
#pragma unroll
            for (int r = 0; r < 4; r++) {
                int row = bm + wave * 32 + mt * 16 + lkg * 4 + r;
                int col = nt * 16 + lrow;
                if (row < M && col < NREAL)
                    Cb[(size_t)row * NREAL + col] = f2b(acc[mt][nt][r]);
            }
}

// ---------------------------------------------------------------------------
// Attention coefficients from bf16 h
// ---------------------------------------------------------------------------
__global__ void att1_kernel(const unsigned short* __restrict__ h1b,
                            const float* __restrict__ att_src,
                            const float* __restrict__ att_dst,
                            float* __restrict__ a_src, float* __restrict__ a_dst,
                            int N) {
    int i = blockIdx.x * blockDim.x + threadIdx.x;
    if (i >= N * 4) return;
    int h = i & 3;
    const ushort4* hp = (const ushort4*)(h1b + (size_t)i * 32);
    const float4* as = (const float4*)(att_src + h * 32);
    const float4* ad = (const float4*)(att_dst + h * 32);
    float ssum = 0.f, dsum = 0.f;
#pragma unroll
    for (int j = 0; j < 8; j++) {
        ushort4 hv = hp[j];
        float4 av = as[j], dv = ad[j];
        float x0 = b2f(hv.x), x1 = b2f(hv.y), x2 = b2f(hv.z), x3 = b2f(hv.w);
        ssum += x0 * av.x + x1 * av.y + x2 * av.z + x3 * av.w;
        dsum += x0 * dv.x + x1 * dv.y + x2 * dv.z + x3 * dv.w;
    }
    a_src[i] = ssum;
    a_dst[i] = dsum;
}

__global__ void att2_kernel(const unsigned short* __restrict__ h2b,
                            const float* __restrict__ att_src,
                            const float* __restrict__ att_dst,
                            float* __restrict__ a_src, float* __restrict__ a_dst,
                            int N) {
    int n = blockIdx.x * blockDim.x + threadIdx.x;
    if (n >= N) return;
    const ushort4* hp = (const ushort4*)(h2b + (size_t)n * 40);
    const float4* as = (const float4*)att_src;
    const float4* ad = (const float4*)att_dst;
    float ssum = 0.f, dsum = 0.f;
#pragma unroll
    for (int j = 0; j < 10; j++) {
        ushort4 hv = hp[j];
        float4 av = as[j], dv = ad[j];
        float x0 = b2f(hv.x), x1 = b2f(hv.y), x2 = b2f(hv.z), x3 = b2f(hv.w);
        ssum += x0 * av.x + x1 * av.y + x2 * av.z + x3 * av.w;
        dsum += x0 * dv.x + x1 * dv.y + x2 * dv.z + x3 * dv.w;
    }
    a_src[n] = ssum;
    a_dst[n] = dsum;
}

// ---------------------------------------------------------------------------
// Aggregation layer 1: softmax (no max-shift; |e|<~6 so exp is safe) over
// incoming edges. 4 heads x 32 dim; block=128 (t=h*32+d), one block per node.
// Weights computed cooperatively once per (edge,head) into LDS, then a
// 2-way-unrolled accumulation with coalesced 256B bf16 gathers.
// ---------------------------------------------------------------------------
__global__ __launch_bounds__(128) void agg1_kernel(
    const unsigned short* __restrict__ h1b, const float* __restrict__ a_src,
    const float* __restrict__ a_dst, const int* __restrict__ rowptr,
    const int* __restrict__ csr_src, const float* __restrict__ b1,
    float* __restrict__ z) {
    const int CH = 256;
    __shared__ int s_src[CH];
    __shared__ float s_w[CH * 4];
    int n = blockIdx.x;
    int t = threadIdx.x;
    int h = t >> 5;                       // head for accumulation (32 dims each)
    float adn_w = a_dst[n * 4 + (t & 3)]; // head for weight phase (j&3 == t&3)
    int beg = rowptr[n];
    int deg = rowptr[n + 1] - beg;

    float acc = 0.f, den = 0.f;
    for (int c0 = 0; c0 < deg; c0 += CH) {
        int cnt = min(CH, deg - c0);
        __syncthreads();                  // prior chunk's LDS reads done
        for (int i = t; i < cnt; i += 128) s_src[i] = csr_src[beg + c0 + i];
        __syncthreads();
        // cooperative weights: task j = edge*(4) + head ; stride 128 keeps j&3 = t&3
        int cnt4 = cnt << 2;
        for (int j = t; j < cnt4; j += 128) {
            int s = s_src[j >> 2];
            float l = a_src[(s << 2) + (t & 3)] + adn_w;
            l = l > 0.f ? l : NEG_SLOPE * l;
            s_w[j] = __expf(l);
        }
        __syncthreads();
        int i = 0;
        for (; i + 1 < cnt; i += 2) {
            int s0 = s_src[i], s1 = s_src[i + 1];
            float w0 = s_w[(i << 2) + h], w1 = s_w[((i + 1) << 2) + h];
            float v0 = b2f(h1b[(size_t)s0 * 128 + t]);
            float v1 = b2f(h1b[(size_t)s1 * 128 + t]);
            den += w0 + w1;
            acc += w0 * v0 + w1 * v1;
        }
        if (i < cnt) {
            int s0 = s_src[i];
            float w0 = s_w[(i << 2) + h];
            den += w0;
            acc += w0 * b2f(h1b[(size_t)s0 * 128 + t]);
        }
    }
    float o = acc / den + b1[t];
    z[(size_t)n * 128 + t] = fmaxf(o, 0.f);   // layer-1 ReLU fused
}

// ---------------------------------------------------------------------------
// Aggregation layer 2: H=1, D=40. One wave per node. Same structure.
// ---------------------------------------------------------------------------
__global__ __launch_bounds__(64) void agg2_kernel(
    const unsigned short* __restrict__ h2b, const float* __restrict__ a_src,
    const float* __restrict__ a_dst, const int* __restrict__ rowptr,
    const int* __restrict__ csr_src, const float* __restrict__ b2,
    float* __restrict__ out) {
    const int CH = 256;
    __shared__ int s_src[CH];
    __shared__ float s_w[CH];
    int n = blockIdx.x;
    int t = threadIdx.x;  // 0..63
    float adn = a_dst[n];
    int beg = rowptr[n];
    int deg = rowptr[n + 1] - beg;

    float acc = 0.f, den = 0.f;
    for (int c0 = 0; c0 < deg; c0 += CH) {
        int cnt = min(CH, deg - c0);
        __syncthreads();
        for (int i = t; i < cnt; i += 64) s_src[i] = csr_src[beg + c0 + i];
        __syncthreads();
        for (int i = t; i < cnt; i += 64) {
            float l = a_src[s_src[i]] + adn;
            l = l > 0.f ? l : NEG_SLOPE * l;
            s_w[i] = __expf(l);
        }
        __syncthreads();
        int i = 0;
        for (; i + 1 < cnt; i += 2) {
            int s0 = s_src[i], s1 = s_src[i + 1];
            float w0 = s_w[i], w1 = s_w[i + 1];
            float v0 = 0.f, v1 = 0.f;
            if (t < 40) {
                v0 = b2f(h2b[(size_t)s0 * 40 + t]);
                v1 = b2f(h2b[(size_t)s1 * 40 + t]);
            }
            den += w0 + w1;
            acc += w0 * v0 + w1 * v1;
        }
        if (i < cnt) {
            int s0 = s_src[i];
            float w0 = s_w[i];
            den += w0;
            if (t < 40) acc += w0 * b2f(h2b[(size_t)s0 * 40 + t]);
        }
    }
    if (t < 40) out[(size_t)n * 40 + t] = acc / den + b2[t];
}

// ---------------------------------------------------------------------------
extern "C" void kernel_launch(void* const* d_in, const int* in_sizes, int n_in,
                              void* d_out, int out_size, void* d_ws, size_t ws_size,
                              hipStream_t stream) {
    const float* x        = (const float*)d_in[0];
    const int*   ei       = (const int*)d_in[1];
    const float* W1       = (const float*)d_in[2];
    const float* att_src1 = (const float*)d_in[3];
    const float* att_dst1 = (const float*)d_in[4];
    const float* b1       = (const float*)d_in[5];
    const float* W2       = (const float*)d_in[6];
    const float* att_src2 = (const float*)d_in[7];
    const float* att_dst2 = (const float*)d_in[8];
    const float* b2       = (const float*)d_in[9];
    float* out = (float*)d_out;

    const int N  = N_NODES;
    const int E0 = in_sizes[1] / 2;
    const int E  = E0 + N;
    const int NCHUNK = (N + 1023) / 1024;  // 49

    char* ws = (char*)d_ws;
    unsigned short* h1b   = (unsigned short*)(ws + 0);          // 12,800,000
    float*          z     = (float*)(ws + 12800000);            // 25,600,000
    unsigned short* h2b   = (unsigned short*)(ws + 38400000);   //  4,000,000
    float* a_src1 = (float*)(ws + 42400000);
    float* a_dst1 = (float*)(ws + 43200000);
    float* a_src2 = (float*)(ws + 44000000);
    float* a_dst2 = (float*)(ws + 44200000);
    int*   deg    = (int*)(ws + 44400000);
    int*   fill   = (int*)(ws + 44600000);
    int*   rowptr = (int*)(ws + 44800000);
    int*   csum   = (int*)(ws + 45000192);
    int*   coff   = (int*)(ws + 45000704);
    int*   csr_src= (int*)(ws + 45001216);

    hipMemsetAsync(deg, 0, 400000, stream);

    count_deg_kernel<<<(E + 255) / 256, 256, 0, stream>>>(ei, E0, E, deg);
    chunk_sum_kernel<<<NCHUNK, 256, 0, stream>>>(deg, csum, N);
    scan_chunks_kernel<<<1, 64, 0, stream>>>(csum, coff, rowptr, NCHUNK, N);
    scan_write_kernel<<<NCHUNK, 1024, 0, stream>>>(deg, coff, rowptr, N);
    scatter_kernel<<<(E + 255) / 256, 256, 0, stream>>>(ei, E0, E, rowptr, fill, csr_src);

    gemm_mfma_kernel<128, 128, 256><<<(N + 127) / 128, 256, 0, stream>>>(x, W1, h1b, N);
    att1_kernel<<<(N * 4 + 255) / 256, 256, 0, stream>>>(h1b, att_src1, att_dst1, a_src1, a_dst1, N);
    agg1_kernel<<<N, 128, 0, stream>>>(h1b, a_src1, a_dst1, rowptr, csr_src, b1, z);

    gemm_mfma_kernel<48, 40, 128><<<(N + 127) / 128, 256, 0, stream>>>(z, W2, h2b, N);
    att2_kernel<<<(N + 255) / 256, 256, 0, stream>>>(h2b, att_src2, att_dst2, a_src2, a_dst2, N);
    agg2_kernel<<<N, 64, 0, stream>>>(h2b, a_src2, a_dst2, rowptr, csr_src, b2, out);
}

// Round 4
// 316.770 us; speedup vs baseline: 1.7439x; 1.1288x over previous
//
#include <hip/hip_runtime.h>
#include <hip/hip_bf16.h>
#include <cstdint>
#include <cstddef>

#define N_NODES 50000
#define NEG_SLOPE 0.2f

typedef float floatx4 __attribute__((ext_vector_type(4)));
typedef short shortx8 __attribute__((ext_vector_type(8)));

// ---- fp32 <-> bf16 helpers (RNE) --------------------------------------------
__device__ __forceinline__ unsigned short f2b(float f) {
    union { float f; unsigned u; } v; v.f = f;
    unsigned u = v.u;
    return (unsigned short)((u + 0x7FFFu + ((u >> 16) & 1u)) >> 16);
}
__device__ __forceinline__ float b2f(unsigned short b) {
    union { unsigned u; float f; } v; v.u = ((unsigned)b) << 16;
    return v.f;
}

// ---------------------------------------------------------------------------
// CSR build: degree count -> hierarchical scan -> scatter
// ---------------------------------------------------------------------------
__global__ void count_deg_kernel(const int* __restrict__ ei, int E0, int E,
                                 int* __restrict__ deg) {
    int e = blockIdx.x * blockDim.x + threadIdx.x;
    if (e >= E) return;
    int d = (e < E0) ? ei[E0 + e] : (e - E0);
    atomicAdd(&deg[d], 1);
}

__global__ void chunk_sum_kernel(const int* __restrict__ deg, int* __restrict__ csum, int n) {
    __shared__ int buf[256];
    int b = blockIdx.x, t = threadIdx.x;
    int base = b * 1024, s = 0;
    for (int i = t; i < 1024; i += 256) {
        int idx = base + i;
        s += (idx < n) ? deg[idx] : 0;
    }
    buf[t] = s; __syncthreads();
    for (int off = 128; off > 0; off >>= 1) {
        if (t < off) buf[t] += buf[t + off];
        __syncthreads();
    }
    if (t == 0) csum[b] = buf[0];
}

__global__ void scan_chunks_kernel(const int* __restrict__ csum, int* __restrict__ coff,
                                   int* __restrict__ rowptr, int nchunks, int n) {
    if (threadIdx.x == 0 && blockIdx.x == 0) {
        int s = 0;
        for (int i = 0; i < nchunks; i++) { coff[i] = s; s += csum[i]; }
        rowptr[n] = s;
    }
}

__global__ __launch_bounds__(1024) void scan_write_kernel(const int* __restrict__ deg,
                                                          const int* __restrict__ coff,
                                                          int* __restrict__ rowptr, int n) {
    __shared__ int buf[1024];
    int b = blockIdx.x, t = threadIdx.x;
    int idx = b * 1024 + t;
    int v = (idx < n) ? deg[idx] : 0;
    int x = v;
    for (int off = 1; off < 1024; off <<= 1) {
        buf[t] = x; __syncthreads();
        int y = (t >= off) ? buf[t - off] : 0;
        __syncthreads();
        x += y;
    }
    if (idx < n) rowptr[idx] = coff[b] + x - v;  // exclusive
}

__global__ void scatter_kernel(const int* __restrict__ ei, int E0, int E,
                               const int* __restrict__ rowptr,
                               int* __restrict__ fill, int* __restrict__ csr_src) {
    int e = blockIdx.x * blockDim.x + threadIdx.x;
    if (e >= E) return;
    int s, d;
    if (e < E0) { s = ei[e]; d = ei[E0 + e]; }
    else        { s = e - E0; d = e - E0; }
    int pos = atomicAdd(&fill[d], 1);
    csr_src[rowptr[d] + pos] = s;
}

// ---------------------------------------------------------------------------
// Single-bf16 MFMA GEMM:  Cb[M,NREAL](bf16) = A[M,KK] x B[NREAL,KK]^T
// InT = float (convert in staging) or ushort (bf16 passthrough). B always fp32.
// BM=64, BK=64, 256 threads / 4 waves; wave w -> rows w*16, all BN cols.
// ---------------------------------------------------------------------------
template <int BM, int BN, int NREAL, int KK, typename InT>
__global__ __launch_bounds__(256) void gemm_bf16_kernel(
    const InT* __restrict__ A, const float* __restrict__ B,
    unsigned short* __restrict__ Cb, int M) {
    const int BK = 64, LDK = 72;   // +8 pad: 2-way-max LDS conflicts (free)
    const int NT = BN / 16;
    __shared__ unsigned short As[BM * LDK];
    __shared__ unsigned short Bs[BN * LDK];
    const int t = threadIdx.x;
    const int wave = t >> 6, lane = t & 63;
    const int lrow = lane & 15, lkg = lane >> 4;
    const int bm = blockIdx.x * BM;

    floatx4 acc[NT] = {};

    for (int k0 = 0; k0 < KK; k0 += BK) {
        __syncthreads();
        if constexpr (sizeof(InT) == 4) {           // fp32 source -> convert
            for (int i = t; i < BM * 16; i += 256) {
                int r = i >> 4, c4 = (i & 15) << 2;
                int gr = bm + r;
                float4 v = make_float4(0.f, 0.f, 0.f, 0.f);
                if (gr < M) v = *(const float4*)&A[(size_t)gr * KK + k0 + c4];
                int o = r * LDK + c4;
                As[o] = f2b(v.x); As[o + 1] = f2b(v.y);
                As[o + 2] = f2b(v.z); As[o + 3] = f2b(v.w);
            }
        } else {                                    // bf16 source -> copy 16B
            for (int i = t; i < BM * 8; i += 256) {
                int r = i >> 3, c8 = (i & 7) << 3;
                int gr = bm + r;
                shortx8 v = {};
                if (gr < M) v = *(const shortx8*)&A[(size_t)gr * KK + k0 + c8];
                *(shortx8*)&As[r * LDK + c8] = v;
            }
        }
        for (int i = t; i < BN * 16; i += 256) {
            int r = i >> 4, c4 = (i & 15) << 2;
            float4 v = make_float4(0.f, 0.f, 0.f, 0.f);
            if (r < NREAL) v = *(const float4*)&B[(size_t)r * KK + k0 + c4];
            int o = r * LDK + c4;
            Bs[o] = f2b(v.x); Bs[o + 1] = f2b(v.y);
            Bs[o + 2] = f2b(v.z); Bs[o + 3] = f2b(v.w);
        }
        __syncthreads();

        for (int ks = 0; ks < BK; ks += 32) {
            int kc = ks + lkg * 8;
            int row = wave * 16 + lrow;
            shortx8 a = *(const shortx8*)&As[row * LDK + kc];
#pragma unroll
            for (int nt = 0; nt < NT; nt++) {
                shortx8 b = *(const shortx8*)&Bs[(nt * 16 + lrow) * LDK + kc];
                acc[nt] = __builtin_amdgcn_mfma_f32_16x16x32_bf16(a, b, acc[nt], 0, 0, 0);
            }
        }
    }
    // C/D layout: col=lane&15, row=(lane>>4)*4+reg (m89-verified)
#pragma unroll
    for (int nt = 0; nt < NT; nt++)
#pragma unroll
        for (int r = 0; r < 4; r++) {
            int row = bm + wave * 16 + lkg * 4 + r;
            int col = nt * 16 + lrow;
            if (row < M && col < NREAL)
                Cb[(size_t)row * NREAL + col] = f2b(acc[nt][r]);
        }
}

// ---------------------------------------------------------------------------
// Attention coefficients from bf16 h
// ---------------------------------------------------------------------------
__global__ void att1_kernel(const unsigned short* __restrict__ h1b,
                            const float* __restrict__ att_src,
                            const float* __restrict__ att_dst,
                            float* __restrict__ a_src, float* __restrict__ a_dst,
                            int N) {
    int i = blockIdx.x * blockDim.x + threadIdx.x;
    if (i >= N * 4) return;
    int h = i & 3;
    const ushort4* hp = (const ushort4*)(h1b + (size_t)i * 32);
    const float4* as = (const float4*)(att_src + h * 32);
    const float4* ad = (const float4*)(att_dst + h * 32);
    float ssum = 0.f, dsum = 0.f;
#pragma unroll
    for (int j = 0; j < 8; j++) {
        ushort4 hv = hp[j];
        float4 av = as[j], dv = ad[j];
        float x0 = b2f(hv.x), x1 = b2f(hv.y), x2 = b2f(hv.z), x3 = b2f(hv.w);
        ssum += x0 * av.x + x1 * av.y + x2 * av.z + x3 * av.w;
        dsum += x0 * dv.x + x1 * dv.y + x2 * dv.z + x3 * dv.w;
    }
    a_src[i] = ssum;
    a_dst[i] = dsum;
}

__global__ void att2_kernel(const unsigned short* __restrict__ h2b,
                            const float* __restrict__ att_src,
                            const float* __restrict__ att_dst,
                            float* __restrict__ a_src, float* __restrict__ a_dst,
                            int N) {
    int n = blockIdx.x * blockDim.x + threadIdx.x;
    if (n >= N) return;
    const ushort4* hp = (const ushort4*)(h2b + (size_t)n * 40);
    const float4* as = (const float4*)att_src;
    const float4* ad = (const float4*)att_dst;
    float ssum = 0.f, dsum = 0.f;
#pragma unroll
    for (int j = 0; j < 10; j++) {
        ushort4 hv = hp[j];
        float4 av = as[j], dv = ad[j];
        float x0 = b2f(hv.x), x1 = b2f(hv.y), x2 = b2f(hv.z), x3 = b2f(hv.w);
        ssum += x0 * av.x + x1 * av.y + x2 * av.z + x3 * av.w;
        dsum += x0 * dv.x + x1 * dv.y + x2 * dv.z + x3 * dv.w;
    }
    a_src[n] = ssum;
    a_dst[n] = dsum;
}

// ---------------------------------------------------------------------------
// Aggregation layer 1: one WAVE per node, register-staged, no LDS/barriers.
// lane: half=l>>5 (edge parity), pos=l&31 (dim group of 4), head=pos>>3.
// Per 16-edge chunk: lane j computes w for (edge j>>2, head j&3); indices and
// weights distributed via __shfl. Gather: ushort4/lane -> 1 wave-instr = 2 rows.
// Softmax without max-shift (|e| small; shift-invariant). z written as bf16.
// ---------------------------------------------------------------------------
__global__ __launch_bounds__(256) void agg1_kernel(
    const unsigned short* __restrict__ h1b, const float* __restrict__ a_src,
    const float* __restrict__ a_dst, const int* __restrict__ rowptr,
    const int* __restrict__ csr_src, const float* __restrict__ b1,
    unsigned short* __restrict__ zb, int N) {
    int wave = threadIdx.x >> 6, lane = threadIdx.x & 63;
    int n = blockIdx.x * 4 + wave;
    if (n >= N) return;                       // wave-uniform
    int half = lane >> 5, pos = lane & 31, head = pos >> 3;
    float adn = a_dst[n * 4 + (lane & 3)];
    int beg = rowptr[n], deg = rowptr[n + 1] - beg;

    floatx4 acc = {0.f, 0.f, 0.f, 0.f};
    float den = 0.f;
    for (int c0 = 0; c0 < deg; c0 += 16) {
        // weight phase: lane j -> edge c0+(j>>2), head j&3
        int idx = c0 + (lane >> 2);
        int s_e = (idx < deg) ? csr_src[beg + idx] : 0;
        float l = a_src[(s_e << 2) + (lane & 3)] + adn;
        l = l > 0.f ? l : NEG_SLOPE * l;
        float w_e = __expf(l);
        int cnt = min(16, deg - c0);
#pragma unroll
        for (int e = 0; e < 16; e += 2) {
            int el = e + half;
            int s = __shfl(s_e, el << 2);
            float w = __shfl(w_e, (el << 2) + head);
            if (el < cnt) {
                ushort4 v = *(const ushort4*)&h1b[(size_t)s * 128 + pos * 4];
                den += w;
                acc.x += w * b2f(v.x); acc.y += w * b2f(v.y);
                acc.z += w * b2f(v.z); acc.w += w * b2f(v.w);
            }
        }
    }
    acc.x += __shfl_xor(acc.x, 32);
    acc.y += __shfl_xor(acc.y, 32);
    acc.z += __shfl_xor(acc.z, 32);
    acc.w += __shfl_xor(acc.w, 32);
    den   += __shfl_xor(den, 32);
    if (half == 0) {
        float inv = 1.f / den;
        float4 bb = *(const float4*)&b1[pos * 4];
        float o0 = fmaxf(acc.x * inv + bb.x, 0.f);
        float o1 = fmaxf(acc.y * inv + bb.y, 0.f);
        float o2 = fmaxf(acc.z * inv + bb.z, 0.f);
        float o3 = fmaxf(acc.w * inv + bb.w, 0.f);
        ushort4 r;
        r.x = f2b(o0); r.y = f2b(o1); r.z = f2b(o2); r.w = f2b(o3);
        *(ushort4*)&zb[(size_t)n * 128 + pos * 4] = r;
    }
}

// ---------------------------------------------------------------------------
// Aggregation layer 2: one wave per node, H=1, D=40, ushort2 per lane (pos<20).
// ---------------------------------------------------------------------------
__global__ __launch_bounds__(256) void agg2_kernel(
    const unsigned short* __restrict__ h2b, const float* __restrict__ a_src,
    const float* __restrict__ a_dst, const int* __restrict__ rowptr,
    const int* __restrict__ csr_src, const float* __restrict__ b2,
    float* __restrict__ out, int N) {
    int wave = threadIdx.x >> 6, lane = threadIdx.x & 63;
    int n = blockIdx.x * 4 + wave;
    if (n >= N) return;
    int half = lane >> 5, pos = lane & 31;
    float adn = a_dst[n];
    int beg = rowptr[n], deg = rowptr[n + 1] - beg;

    float2 acc = {0.f, 0.f};
    float den = 0.f;
    for (int c0 = 0; c0 < deg; c0 += 32) {
        int idx = c0 + lane;
        int s_e = (idx < deg) ? csr_src[beg + idx] : 0;
        float l = a_src[s_e] + adn;
        l = l > 0.f ? l : NEG_SLOPE * l;
        float w_e = __expf(l);
        int cnt = min(32, deg - c0);
#pragma unroll
        for (int e = 0; e < 32; e += 2) {
            int el = e + half;
            int s = __shfl(s_e, el);
            float w = __shfl(w_e, el);
            if (el < cnt) {
                den += w;
                if (pos < 20) {
                    ushort2 v = *(const ushort2*)&h2b[(size_t)s * 40 + pos * 2];
                    acc.x += w * b2f(v.x);
                    acc.y += w * b2f(v.y);
                }
            }
        }
    }
    acc.x += __shfl_xor(acc.x, 32);
    acc.y += __shfl_xor(acc.y, 32);
    den   += __shfl_xor(den, 32);
    if (half == 0 && pos < 20) {
        float inv = 1.f / den;
        float2 bb = *(const float2*)&b2[pos * 2];
        float2 o;
        o.x = acc.x * inv + bb.x;
        o.y = acc.y * inv + bb.y;
        *(float2*)&out[(size_t)n * 40 + pos * 2] = o;
    }
}

// ---------------------------------------------------------------------------
extern "C" void kernel_launch(void* const* d_in, const int* in_sizes, int n_in,
                              void* d_out, int out_size, void* d_ws, size_t ws_size,
                              hipStream_t stream) {
    const float* x        = (const float*)d_in[0];
    const int*   ei       = (const int*)d_in[1];
    const float* W1       = (const float*)d_in[2];
    const float* att_src1 = (const float*)d_in[3];
    const float* att_dst1 = (const float*)d_in[4];
    const float* b1       = (const float*)d_in[5];
    const float* W2       = (const float*)d_in[6];
    const float* att_src2 = (const float*)d_in[7];
    const float* att_dst2 = (const float*)d_in[8];
    const float* b2       = (const float*)d_in[9];
    float* out = (float*)d_out;

    const int N  = N_NODES;
    const int E0 = in_sizes[1] / 2;
    const int E  = E0 + N;
    const int NCHUNK = (N + 1023) / 1024;  // 49

    char* ws = (char*)d_ws;
    unsigned short* h1b = (unsigned short*)(ws + 0);          // 12,800,000
    unsigned short* zb  = (unsigned short*)(ws + 12800000);   // 12,800,000
    unsigned short* h2b = (unsigned short*)(ws + 25600000);   //  4,000,000
    float* a_src1 = (float*)(ws + 29600000);                  //    800,000
    float* a_dst1 = (float*)(ws + 30400000);                  //    800,000
    float* a_src2 = (float*)(ws + 31200000);                  //    200,000
    float* a_dst2 = (float*)(ws + 31400000);                  //    200,000
    int*   deg    = (int*)(ws + 31600000);                    //    200,000
    int*   fill   = (int*)(ws + 31800000);                    //    200,000
    int*   rowptr = (int*)(ws + 32000000);                    //    200,004
    int*   csum   = (int*)(ws + 32200192);                    //        512
    int*   coff   = (int*)(ws + 32200704);                    //        512
    int*   csr_src= (int*)(ws + 32201216);                    //  3,400,000

    hipMemsetAsync(deg, 0, 400000, stream);   // deg + fill contiguous

    count_deg_kernel<<<(E + 255) / 256, 256, 0, stream>>>(ei, E0, E, deg);
    chunk_sum_kernel<<<NCHUNK, 256, 0, stream>>>(deg, csum, N);
    scan_chunks_kernel<<<1, 64, 0, stream>>>(csum, coff, rowptr, NCHUNK, N);
    scan_write_kernel<<<NCHUNK, 1024, 0, stream>>>(deg, coff, rowptr, N);
    scatter_kernel<<<(E + 255) / 256, 256, 0, stream>>>(ei, E0, E, rowptr, fill, csr_src);

    // layer 1: h1b = bf16(x @ W1^T)
    gemm_bf16_kernel<64, 128, 128, 256, float>
        <<<(N + 63) / 64, 256, 0, stream>>>(x, W1, h1b, N);
    att1_kernel<<<(N * 4 + 255) / 256, 256, 0, stream>>>(h1b, att_src1, att_dst1, a_src1, a_dst1, N);
    agg1_kernel<<<(N + 3) / 4, 256, 0, stream>>>(h1b, a_src1, a_dst1, rowptr, csr_src, b1, zb, N);

    // layer 2: h2b = bf16(zb @ W2^T)
    gemm_bf16_kernel<64, 48, 40, 128, unsigned short>
        <<<(N + 63) / 64, 256, 0, stream>>>(zb, W2, h2b, N);
    att2_kernel<<<(N + 255) / 256, 256, 0, stream>>>(h2b, att_src2, att_dst2, a_src2, a_dst2, N);
    agg2_kernel<<<(N + 3) / 4, 256, 0, stream>>>(h2b, a_src2, a_dst2, rowptr, csr_src, b2, out, N);
}

// Round 5
// 267.407 us; speedup vs baseline: 2.0659x; 1.1846x over previous
//
#include <hip/hip_runtime.h>
#include <hip/hip_bf16.h>
#include <cstdint>
#include <cstddef>

#define N_NODES 50000
#define NEG_SLOPE 0.2f
#define NB 196            // buckets of 256 nodes: (50000+255)/256
#define BIN_CHUNK 8192    // edges per block in hist/bin kernels
#define SLICE_MAX 14336   // LDS slice capacity (mean ~4345, 3.3x headroom)

typedef float floatx4 __attribute__((ext_vector_type(4)));
typedef short shortx8 __attribute__((ext_vector_type(8)));

// ---- fp32 <-> bf16 helpers (RNE) --------------------------------------------
__device__ __forceinline__ unsigned short f2b(float f) {
    union { float f; unsigned u; } v; v.f = f;
    unsigned u = v.u;
    return (unsigned short)((u + 0x7FFFu + ((u >> 16) & 1u)) >> 16);
}
__device__ __forceinline__ float b2f(unsigned short b) {
    union { unsigned u; float f; } v; v.u = ((unsigned)b) << 16;
    return v.f;
}

// ---------------------------------------------------------------------------
// CSR build, bucketed multisplit.
// K1: bucket histogram (LDS per block, 196 global atomics per block)
// ---------------------------------------------------------------------------
__global__ __launch_bounds__(256) void bucket_hist_kernel(
    const int* __restrict__ ei, int E0, int E, int* __restrict__ bhist) {
    __shared__ int h[NB];
    int t = threadIdx.x;
    for (int i = t; i < NB; i += 256) h[i] = 0;
    __syncthreads();
    int base = blockIdx.x * BIN_CHUNK;
    int end = min(base + BIN_CHUNK, E);
    for (int e = base + t; e < end; e += 256) {
        int d = (e < E0) ? ei[E0 + e] : (e - E0);
        atomicAdd(&h[d >> 8], 1);
    }
    __syncthreads();
    for (int i = t; i < NB; i += 256)
        if (h[i]) atomicAdd(&bhist[i], h[i]);
}

// K2: scan 196 bucket counts -> bbase[NB+1], init bcursor, rowptr[N]=E
__global__ __launch_bounds__(256) void bucket_scan_kernel(
    const int* __restrict__ bhist, int* __restrict__ bbase,
    int* __restrict__ bcursor, int* __restrict__ rowptr, int E) {
    __shared__ int buf[256];
    int t = threadIdx.x;
    int v = (t < NB) ? bhist[t] : 0;
    int x = v;
    for (int off = 1; off < 256; off <<= 1) {
        buf[t] = x; __syncthreads();
        int y = (t >= off) ? buf[t - off] : 0;
        __syncthreads();
        x += y;
    }
    if (t < NB) {
        bbase[t] = x - v;      // exclusive
        bcursor[t] = x - v;
    }
    if (t == NB - 1) bbase[NB] = x;
    if (t == 0) rowptr[N_NODES] = E;
}

// K3: bin edges into bucket regions, packed src|(dst&255)<<16, burst writes
__global__ __launch_bounds__(256) void bin_kernel(
    const int* __restrict__ ei, int E0, int E,
    int* __restrict__ bcursor, unsigned int* __restrict__ ebuf) {
    __shared__ int h[NB];
    __shared__ int gbase[NB];
    int t = threadIdx.x;
    for (int i = t; i < NB; i += 256) h[i] = 0;
    __syncthreads();
    int base = blockIdx.x * BIN_CHUNK;
    int end = min(base + BIN_CHUNK, E);
    // pass 1: local histogram
    for (int e = base + t; e < end; e += 256) {
        int d = (e < E0) ? ei[E0 + e] : (e - E0);
        atomicAdd(&h[d >> 8], 1);
    }
    __syncthreads();
    // reserve global bursts
    for (int i = t; i < NB; i += 256) {
        int c = h[i];
        gbase[i] = c ? atomicAdd(&bcursor[i], c) : 0;
        h[i] = 0;  // reuse as local cursor
    }
    __syncthreads();
    // pass 2: re-read (L2-hot) and place
    for (int e = base + t; e < end; e += 256) {
        int s, d;
        if (e < E0) { s = ei[e]; d = ei[E0 + e]; }
        else        { s = e - E0; d = e - E0; }
        int b = d >> 8;
        int off = atomicAdd(&h[b], 1);
        ebuf[gbase[b] + off] = (unsigned)s | ((unsigned)(d & 255) << 16);
    }
}

// K4: one block per bucket: local deg-hist -> rowptr, LDS-staged CSR slice,
// fully-coalesced slice write. Replaces count_deg + node scans + scatter.
__global__ __launch_bounds__(256) void build_kernel(
    const unsigned int* __restrict__ ebuf, const int* __restrict__ bbase,
    int* __restrict__ rowptr, int* __restrict__ csr_src) {
    __shared__ int h[256];
    __shared__ int lrp[257];
    __shared__ int stag[SLICE_MAX];
    int b = blockIdx.x, t = threadIdx.x;
    int e0 = bbase[b], e1 = bbase[b + 1];
    int cnt = e1 - e0;
    int n0 = b << 8;
    h[t] = 0;
    __syncthreads();
    // pass A: per-node degree histogram
    for (int i = t; i < cnt; i += 256)
        atomicAdd(&h[ebuf[e0 + i] >> 16], 1);
    __syncthreads();
    // scan 256 -> exclusive lrp
    int v = h[t], x = v;
    __shared__ int buf[256];
    for (int off = 1; off < 256; off <<= 1) {
        buf[t] = x; __syncthreads();
        int y = (t >= off) ? buf[t - off] : 0;
        __syncthreads();
        x += y;
    }
    lrp[t] = x - v;
    if (t == 255) lrp[256] = x;
    h[t] = 0;  // reuse as fill counters
    __syncthreads();
    int n = n0 + t;
    if (n < N_NODES) rowptr[n] = e0 + lrp[t];
    // pass B: place srcs into LDS slice
    for (int i = t; i < cnt; i += 256) {
        unsigned int v2 = ebuf[e0 + i];
        int dloc = v2 >> 16;
        int off = atomicAdd(&h[dloc], 1);
        stag[lrp[dloc] + off] = (int)(v2 & 0xFFFFu);
    }
    __syncthreads();
    // pass C: coalesced slice write-out
    for (int i = t; i < cnt; i += 256) csr_src[e0 + i] = stag[i];
}

// ---------------------------------------------------------------------------
// Single-bf16 MFMA GEMM:  Cb[M,NREAL](bf16) = A[M,KK] x B[NREAL,KK]^T
// ---------------------------------------------------------------------------
template <int BM, int BN, int NREAL, int KK, typename InT>
__global__ __launch_bounds__(256) void gemm_bf16_kernel(
    const InT* __restrict__ A, const float* __restrict__ B,
    unsigned short* __restrict__ Cb, int M) {
    const int BK = 64, LDK = 72;
    const int NT = BN / 16;
    __shared__ unsigned short As[BM * LDK];
    __shared__ unsigned short Bs[BN * LDK];
    const int t = threadIdx.x;
    const int wave = t >> 6, lane = t & 63;
    const int lrow = lane & 15, lkg = lane >> 4;
    const int bm = blockIdx.x * BM;

    floatx4 acc[NT] = {};

    for (int k0 = 0; k0 < KK; k0 += BK) {
        __syncthreads();
        if constexpr (sizeof(InT) == 4) {
            for (int i = t; i < BM * 16; i += 256) {
                int r = i >> 4, c4 = (i & 15) << 2;
                int gr = bm + r;
                float4 v = make_float4(0.f, 0.f, 0.f, 0.f);
                if (gr < M) v = *(const float4*)&A[(size_t)gr * KK + k0 + c4];
                int o = r * LDK + c4;
                As[o] = f2b(v.x); As[o + 1] = f2b(v.y);
                As[o + 2] = f2b(v.z); As[o + 3] = f2b(v.w);
            }
        } else {
            for (int i = t; i < BM * 8; i += 256) {
                int r = i >> 3, c8 = (i & 7) << 3;
                int gr = bm + r;
                shortx8 v = {};
                if (gr < M) v = *(const shortx8*)&A[(size_t)gr * KK + k0 + c8];
                *(shortx8*)&As[r * LDK + c8] = v;
            }
        }
        for (int i = t; i < BN * 16; i += 256) {
            int r = i >> 4, c4 = (i & 15) << 2;
            float4 v = make_float4(0.f, 0.f, 0.f, 0.f);
            if (r < NREAL) v = *(const float4*)&B[(size_t)r * KK + k0 + c4];
            int o = r * LDK + c4;
            Bs[o] = f2b(v.x); Bs[o + 1] = f2b(v.y);
            Bs[o + 2] = f2b(v.z); Bs[o + 3] = f2b(v.w);
        }
        __syncthreads();

        for (int ks = 0; ks < BK; ks += 32) {
            int kc = ks + lkg * 8;
            int row = wave * 16 + lrow;
            shortx8 a = *(const shortx8*)&As[row * LDK + kc];
#pragma unroll
            for (int nt = 0; nt < NT; nt++) {
                shortx8 b = *(const shortx8*)&Bs[(nt * 16 + lrow) * LDK + kc];
                acc[nt] = __builtin_amdgcn_mfma_f32_16x16x32_bf16(a, b, acc[nt], 0, 0, 0);
            }
        }
    }
#pragma unroll
    for (int nt = 0; nt < NT; nt++)
#pragma unroll
        for (int r = 0; r < 4; r++) {
            int row = bm + wave * 16 + lkg * 4 + r;
            int col = nt * 16 + lrow;
            if (row < M && col < NREAL)
                Cb[(size_t)row * NREAL + col] = f2b(acc[nt][r]);
        }
}

// ---------------------------------------------------------------------------
// Attention coefficients from bf16 h
// ---------------------------------------------------------------------------
__global__ void att1_kernel(const unsigned short* __restrict__ h1b,
                            const float* __restrict__ att_src,
                            const float* __restrict__ att_dst,
                            float* __restrict__ a_src, float* __restrict__ a_dst,
                            int N) {
    int i = blockIdx.x * blockDim.x + threadIdx.x;
    if (i >= N * 4) return;
    int h = i & 3;
    const ushort4* hp = (const ushort4*)(h1b + (size_t)i * 32);
    const float4* as = (const float4*)(att_src + h * 32);
    const float4* ad = (const float4*)(att_dst + h * 32);
    float ssum = 0.f, dsum = 0.f;
#pragma unroll
    for (int j = 0; j < 8; j++) {
        ushort4 hv = hp[j];
        float4 av = as[j], dv = ad[j];
        float x0 = b2f(hv.x), x1 = b2f(hv.y), x2 = b2f(hv.z), x3 = b2f(hv.w);
        ssum += x0 * av.x + x1 * av.y + x2 * av.z + x3 * av.w;
        dsum += x0 * dv.x + x1 * dv.y + x2 * dv.z + x3 * dv.w;
    }
    a_src[i] = ssum;
    a_dst[i] = dsum;
}

__global__ void att2_kernel(const unsigned short* __restrict__ h2b,
                            const float* __restrict__ att_src,
                            const float* __restrict__ att_dst,
                            float* __restrict__ a_src, float* __restrict__ a_dst,
                            int N) {
    int n = blockIdx.x * blockDim.x + threadIdx.x;
    if (n >= N) return;
    const ushort4* hp = (const ushort4*)(h2b + (size_t)n * 40);
    const float4* as = (const float4*)att_src;
    const float4* ad = (const float4*)att_dst;
    float ssum = 0.f, dsum = 0.f;
#pragma unroll
    for (int j = 0; j < 10; j++) {
        ushort4 hv = hp[j];
        float4 av = as[j], dv = ad[j];
        float x0 = b2f(hv.x), x1 = b2f(hv.y), x2 = b2f(hv.z), x3 = b2f(hv.w);
        ssum += x0 * av.x + x1 * av.y + x2 * av.z + x3 * av.w;
        dsum += x0 * dv.x + x1 * dv.y + x2 * dv.z + x3 * dv.w;
    }
    a_src[n] = ssum;
    a_dst[n] = dsum;
}

// ---------------------------------------------------------------------------
// Aggregation layer 1: one WAVE per node, register-staged, no LDS/barriers.
// ---------------------------------------------------------------------------
__global__ __launch_bounds__(256) void agg1_kernel(
    const unsigned short* __restrict__ h1b, const float* __restrict__ a_src,
    const float* __restrict__ a_dst, const int* __restrict__ rowptr,
    const int* __restrict__ csr_src, const float* __restrict__ b1,
    unsigned short* __restrict__ zb, int N) {
    int wave = threadIdx.x >> 6, lane = threadIdx.x & 63;
    int n = blockIdx.x * 4 + wave;
    if (n >= N) return;
    int half = lane >> 5, pos = lane & 31, head = pos >> 3;
    float adn = a_dst[n * 4 + (lane & 3)];
    int beg = rowptr[n], deg = rowptr[n + 1] - beg;

    floatx4 acc = {0.f, 0.f, 0.f, 0.f};
    float den = 0.f;
    for (int c0 = 0; c0 < deg; c0 += 16) {
        int idx = c0 + (lane >> 2);
        int s_e = (idx < deg) ? csr_src[beg + idx] : 0;
        float l = a_src[(s_e << 2) + (lane & 3)] + adn;
        l = l > 0.f ? l : NEG_SLOPE * l;
        float w_e = __expf(l);
        int cnt = min(16, deg - c0);
#pragma unroll
        for (int e = 0; e < 16; e += 2) {
            int el = e + half;
            int s = __shfl(s_e, el << 2);
            float w = __shfl(w_e, (el << 2) + head);
            if (el < cnt) {
                ushort4 v = *(const ushort4*)&h1b[(size_t)s * 128 + pos * 4];
                den += w;
                acc.x += w * b2f(v.x); acc.y += w * b2f(v.y);
                acc.z += w * b2f(v.z); acc.w += w * b2f(v.w);
            }
        }
    }
    acc.x += __shfl_xor(acc.x, 32);
    acc.y += __shfl_xor(acc.y, 32);
    acc.z += __shfl_xor(acc.z, 32);
    acc.w += __shfl_xor(acc.w, 32);
    den   += __shfl_xor(den, 32);
    if (half == 0) {
        float inv = 1.f / den;
        float4 bb = *(const float4*)&b1[pos * 4];
        float o0 = fmaxf(acc.x * inv + bb.x, 0.f);
        float o1 = fmaxf(acc.y * inv + bb.y, 0.f);
        float o2 = fmaxf(acc.z * inv + bb.z, 0.f);
        float o3 = fmaxf(acc.w * inv + bb.w, 0.f);
        ushort4 r;
        r.x = f2b(o0); r.y = f2b(o1); r.z = f2b(o2); r.w = f2b(o3);
        *(ushort4*)&zb[(size_t)n * 128 + pos * 4] = r;
    }
}

// ---------------------------------------------------------------------------
// Aggregation layer 2: one wave per node, H=1, D=40.
// ---------------------------------------------------------------------------
__global__ __launch_bounds__(256) void agg2_kernel(
    const unsigned short* __restrict__ h2b, const float* __restrict__ a_src,
    const float* __restrict__ a_dst, const int* __restrict__ rowptr,
    const int* __restrict__ csr_src, const float* __restrict__ b2,
    float* __restrict__ out, int N) {
    int wave = threadIdx.x >> 6, lane = threadIdx.x & 63;
    int n = blockIdx.x * 4 + wave;
    if (n >= N) return;
    int half = lane >> 5, pos = lane & 31;
    float adn = a_dst[n];
    int beg = rowptr[n], deg = rowptr[n + 1] - beg;

    float2 acc = {0.f, 0.f};
    float den = 0.f;
    for (int c0 = 0; c0 < deg; c0 += 32) {
        int idx = c0 + lane;
        int s_e = (idx < deg) ? csr_src[beg + idx] : 0;
        float l = a_src[s_e] + adn;
        l = l > 0.f ? l : NEG_SLOPE * l;
        float w_e = __expf(l);
        int cnt = min(32, deg - c0);
#pragma unroll
        for (int e = 0; e < 32; e += 2) {
            int el = e + half;
            int s = __shfl(s_e, el);
            float w = __shfl(w_e, el);
            if (el < cnt) {
                den += w;
                if (pos < 20) {
                    ushort2 v = *(const ushort2*)&h2b[(size_t)s * 40 + pos * 2];
                    acc.x += w * b2f(v.x);
                    acc.y += w * b2f(v.y);
                }
            }
        }
    }
    acc.x += __shfl_xor(acc.x, 32);
    acc.y += __shfl_xor(acc.y, 32);
    den   += __shfl_xor(den, 32);
    if (half == 0 && pos < 20) {
        float inv = 1.f / den;
        float2 bb = *(const float2*)&b2[pos * 2];
        float2 o;
        o.x = acc.x * inv + bb.x;
        o.y = acc.y * inv + bb.y;
        *(float2*)&out[(size_t)n * 40 + pos * 2] = o;
    }
}

// ---------------------------------------------------------------------------
extern "C" void kernel_launch(void* const* d_in, const int* in_sizes, int n_in,
                              void* d_out, int out_size, void* d_ws, size_t ws_size,
                              hipStream_t stream) {
    const float* x        = (const float*)d_in[0];
    const int*   ei       = (const int*)d_in[1];
    const float* W1       = (const float*)d_in[2];
    const float* att_src1 = (const float*)d_in[3];
    const float* att_dst1 = (const float*)d_in[4];
    const float* b1       = (const float*)d_in[5];
    const float* W2       = (const float*)d_in[6];
    const float* att_src2 = (const float*)d_in[7];
    const float* att_dst2 = (const float*)d_in[8];
    const float* b2       = (const float*)d_in[9];
    float* out = (float*)d_out;

    const int N  = N_NODES;
    const int E0 = in_sizes[1] / 2;
    const int E  = E0 + N;
    const int NBLK = (E + BIN_CHUNK - 1) / BIN_CHUNK;

    char* ws = (char*)d_ws;
    unsigned short* h1b = (unsigned short*)(ws + 0);          // 12,800,000
    unsigned short* zb  = (unsigned short*)(ws + 12800000);   // 12,800,000
    unsigned short* h2b = (unsigned short*)(ws + 25600000);   //  4,000,000
    float* a_src1 = (float*)(ws + 29600000);                  //    800,000
    float* a_dst1 = (float*)(ws + 30400000);                  //    800,000
    float* a_src2 = (float*)(ws + 31200000);                  //    200,000
    float* a_dst2 = (float*)(ws + 31400000);                  //    200,000
    int*   rowptr = (int*)(ws + 31600000);                    //    200,004
    int*   bhist  = (int*)(ws + 31800192);                    //        784
    int*   bbase  = (int*)(ws + 31801088);                    //        788
    int*   bcursor= (int*)(ws + 31801984);                    //        784
    unsigned int* ebuf = (unsigned int*)(ws + 31802880);      //  3,400,000
    int*   csr_src= (int*)(ws + 35202880);                    //  3,400,000
    // total ~38.6 MB

    hipMemsetAsync(bhist, 0, NB * sizeof(int), stream);

    bucket_hist_kernel<<<NBLK, 256, 0, stream>>>(ei, E0, E, bhist);
    bucket_scan_kernel<<<1, 256, 0, stream>>>(bhist, bbase, bcursor, rowptr, E);
    bin_kernel<<<NBLK, 256, 0, stream>>>(ei, E0, E, bcursor, ebuf);
    build_kernel<<<NB, 256, 0, stream>>>(ebuf, bbase, rowptr, csr_src);

    // layer 1: h1b = bf16(x @ W1^T)
    gemm_bf16_kernel<64, 128, 128, 256, float>
        <<<(N + 63) / 64, 256, 0, stream>>>(x, W1, h1b, N);
    att1_kernel<<<(N * 4 + 255) / 256, 256, 0, stream>>>(h1b, att_src1, att_dst1, a_src1, a_dst1, N);
    agg1_kernel<<<(N + 3) / 4, 256, 0, stream>>>(h1b, a_src1, a_dst1, rowptr, csr_src, b1, zb, N);

    // layer 2: h2b = bf16(zb @ W2^T)
    gemm_bf16_kernel<64, 48, 40, 128, unsigned short>
        <<<(N + 63) / 64, 256, 0, stream>>>(zb, W2, h2b, N);
    att2_kernel<<<(N + 255) / 256, 256, 0, stream>>>(h2b, att_src2, att_dst2, a_src2, a_dst2, N);
    agg2_kernel<<<(N + 3) / 4, 256, 0, stream>>>(h2b, a_src2, a_dst2, rowptr, csr_src, b2, out, N);
}